// Round 6
// baseline (13.315 us; speedup 1.0000x reference)
//
#include <hip/hip_runtime.h>
#include <math.h>

// MultiBiasEncoder, fused single-kernel, l-parallel coefficient phase.
//   out[p,c] = sum_s A_s[p]*w[s,c] + sum_s B_s[p]*k[s,c] + sum_l lwn_l[p]*le[l,c] + cnst[p]
// Closed-form LN stats: mean = d*mw+mk ; var = d^2*vw + d*cwk2 + vk.
// Phase S: wave wid butterflies stats for s in {wid, wid+4, wid+8} -> LDS; ONE barrier.
// Phase A: 8 sub-lanes per position; sub-lane q<5 handles location l=q (L-loop collapsed
//          to a single iteration); 24-coef vector reduced over the 8-lane group via
//          3-stage shfl_xor butterfly; sub-lane 0 writes coefs to this wave's LDS rows.
//          (same-wave LDS produce/consume: no second barrier)
// Phase B: each wave applies its own 8 positions; 6 broadcast float4 reads + 25 FMA; coalesced store.
// scale-log factorization: log(|d|/s+eps) ~= max(log|d| - log s, log eps)  (verified R4/R5)

#define EPS_W 1e-6f
#define LN_EPS 1e-5f
#define LOG_EPS -13.815511f   // ln(1e-6)

constexpr int L = 5;
constexpr int S = 9;
constexpr int C = 64;
constexpr int PW = 8;     // positions per wave
constexpr int POS = 32;   // positions per block (4 waves)

__device__ __forceinline__ float fastrcp(float v) { return __builtin_amdgcn_rcpf(v); }

__global__ __launch_bounds__(256) void mbe5_kernel(
    const float* __restrict__ x,
    const float* __restrict__ ws,
    const float* __restrict__ bs,
    const float* __restrict__ loc_emb,
    const float* __restrict__ scales,
    const float* __restrict__ locs,
    float* __restrict__ out,
    int npos)
{
    const int tid = threadIdx.x;
    const int lane = tid & 63;
    const int wid = tid >> 6;

    __shared__ float4 statsLds[S][2];    // [s][0]={mw,mk,vw,cwk2} [s][1]={vk,log(scale),-,-}
    __shared__ float4 coefLds[POS][6];   // 24 coefs per position

    const int pbase = blockIdx.x * POS + wid * PW;  // this wave's first position
    const int q = lane & 7;    // sub-lane within 8-lane position group
    const int gi = lane >> 3;  // position index within wave (0..7)
    const int p = pbase + gi;  // phase-A position for this lane's group

    // ---- early x broadcast load (8 lanes share one position) ----
    const int pc = p < npos ? p : (npos - 1);
    const float xv = x[pc];

    // ---- per-thread channel tables (lane == channel) ----
    float w[S], k[S], le[L];
#pragma unroll
    for (int s = 0; s < S; ++s) {
        w[s] = ws[s * C + lane];
        k[s] = bs[s * C + lane] * scales[s];
    }
#pragma unroll
    for (int l = 0; l < L; ++l) le[l] = loc_emb[l * C + lane];

    // ---- Phase S: distributed LN-stat butterflies (wave wid: s = wid, wid+4, wid+8) ----
    for (int s = wid; s < S; s += 4) {
        float a0 = w[s], a1 = k[s];
        float a2 = w[s] * w[s], a3 = w[s] * k[s], a4 = k[s] * k[s];
#pragma unroll
        for (int off = 32; off; off >>= 1) {
            a0 += __shfl_xor(a0, off);
            a1 += __shfl_xor(a1, off);
            a2 += __shfl_xor(a2, off);
            a3 += __shfl_xor(a3, off);
            a4 += __shfl_xor(a4, off);
        }
        if (lane == 0) {
            float mww = a0 * (1.0f / 64.0f);
            float mkk = a1 * (1.0f / 64.0f);
            statsLds[s][0] = make_float4(
                mww, mkk,
                fmaf(-mww, mww, a2 * (1.0f / 64.0f)),            // vw
                2.0f * fmaf(-mww, mkk, a3 * (1.0f / 64.0f)));    // cwk2
            statsLds[s][1] = make_float4(
                fmaf(-mkk, mkk, a4 * (1.0f / 64.0f)),            // vk
                __logf(scales[s]), 0.0f, 0.0f);
        }
    }
    __syncthreads();

    // ---- Phase A: sub-lane q handles location l=q for its group's position ----
    float cf[24];
#pragma unroll
    for (int j = 0; j < 24; ++j) cf[j] = 0.0f;

    float lwv = 0.0f, llog_ = 0.0f, dl = 0.0f;
    const bool act = (q < L) && (p < npos);
    if (act) {
        dl = xv - locs[q];
        float ad = fabsf(dl);
        lwv = fastrcp(__logf(ad + 1.0f) + EPS_W);
        llog_ = __logf(ad);   // -inf at ad=0 clamped by fmax below
    }
    // location-weight sum over the 8-lane group (inactive lanes contribute 0)
    float lwsum = lwv;
    lwsum += __shfl_xor(lwsum, 1);
    lwsum += __shfl_xor(lwsum, 2);
    lwsum += __shfl_xor(lwsum, 4);
    const float lwn = lwv * fastrcp(lwsum);   // 0 on inactive lanes
    // scatter lwn into cf[18+l] with static indices (rule #20: no runtime reg index)
    cf[18] = (q == 0) ? lwn : 0.0f;
    cf[19] = (q == 1) ? lwn : 0.0f;
    cf[20] = (q == 2) ? lwn : 0.0f;
    cf[21] = (q == 3) ? lwn : 0.0f;
    cf[22] = (q == 4) ? lwn : 0.0f;

    if (act) {
        float swv[S];
        float ssum = 0.0f;
#pragma unroll
        for (int s = 0; s < S; ++s) {
            float lg = statsLds[s][1].y;
            float u = fmaxf(llog_ - lg, LOG_EPS);   // ~ log(|d|/scale + eps)
            swv[s] = fastrcp(fabsf(u) + EPS_W);
            ssum += swv[s];
        }
        const float rss = fastrcp(ssum) * lwn;
        const float d2 = dl * dl;
#pragma unroll
        for (int s = 0; s < S; ++s) {
            float4 a = statsLds[s][0];
            float4 b = statsLds[s][1];
            float mean = fmaf(dl, a.x, a.y);
            float var = fmaf(d2, a.z, fmaf(dl, a.w, b.x));
            float rstd = rsqrtf(var + LN_EPS);
            float alpha = swv[s] * rss * rstd;
            cf[s] = alpha * dl;                       // A_s (single l per lane)
            cf[9 + s] = alpha;                        // B_s
            cf[23] = fmaf(-alpha, mean, cf[23]);      // const (accumulated over s)
        }
    }

    // 3-stage butterfly over the 8-lane group: sums the 5 location contributions
#pragma unroll
    for (int off = 1; off <= 4; off <<= 1) {
#pragma unroll
        for (int j = 0; j < 24; ++j) cf[j] += __shfl_xor(cf[j], off);
    }

    if (q == 0 && p < npos) {
        const int row = wid * PW + gi;
#pragma unroll
        for (int j = 0; j < 6; ++j)
            coefLds[row][j] = make_float4(cf[4 * j], cf[4 * j + 1],
                                          cf[4 * j + 2], cf[4 * j + 3]);
    }
    // NO __syncthreads: each wave reads only rows it wrote itself (lgkmcnt-ordered).

    // ---- Phase B: each wave applies its own 8 positions ----
#pragma unroll
    for (int i = 0; i < PW; ++i) {
        const int pp = pbase + i;
        if (pp >= npos) break;
        const int row = wid * PW + i;
        float4 q0 = coefLds[row][0];
        float4 q1 = coefLds[row][1];
        float4 q2 = coefLds[row][2];
        float4 q3 = coefLds[row][3];
        float4 q4 = coefLds[row][4];
        float4 q5 = coefLds[row][5];
        // A[0..8]=q0.xyzw q1.xyzw q2.x ; B[0..8]=q2.yzw q3.xyzw q4.xy
        // lwn[0..4]=q4.zw q5.xyz ; cnst=q5.w
        float acc = q5.w;
        acc = fmaf(q0.x, w[0], acc); acc = fmaf(q0.y, w[1], acc);
        acc = fmaf(q0.z, w[2], acc); acc = fmaf(q0.w, w[3], acc);
        acc = fmaf(q1.x, w[4], acc); acc = fmaf(q1.y, w[5], acc);
        acc = fmaf(q1.z, w[6], acc); acc = fmaf(q1.w, w[7], acc);
        acc = fmaf(q2.x, w[8], acc);
        acc = fmaf(q2.y, k[0], acc); acc = fmaf(q2.z, k[1], acc);
        acc = fmaf(q2.w, k[2], acc); acc = fmaf(q3.x, k[3], acc);
        acc = fmaf(q3.y, k[4], acc); acc = fmaf(q3.z, k[5], acc);
        acc = fmaf(q3.w, k[6], acc); acc = fmaf(q4.x, k[7], acc);
        acc = fmaf(q4.y, k[8], acc);
        acc = fmaf(q4.z, le[0], acc); acc = fmaf(q4.w, le[1], acc);
        acc = fmaf(q5.x, le[2], acc); acc = fmaf(q5.y, le[3], acc);
        acc = fmaf(q5.z, le[4], acc);
        out[(size_t)pp * C + lane] = acc;
    }
}

extern "C" void kernel_launch(void* const* d_in, const int* in_sizes, int n_in,
                              void* d_out, int out_size, void* d_ws, size_t ws_size,
                              hipStream_t stream) {
    const float* x = (const float*)d_in[0];
    const float* ws = (const float*)d_in[1];
    const float* bs = (const float*)d_in[2];
    const float* loc_emb = (const float*)d_in[3];
    const float* scales = (const float*)d_in[4];
    const float* locs = (const float*)d_in[5];
    float* out = (float*)d_out;

    int npos = in_sizes[0];  // B*T = 16384
    int blocks = (npos + POS - 1) / POS;  // 512 -> 2 blocks/CU, 2 waves/SIMD
    mbe5_kernel<<<blocks, 256, 0, stream>>>(x, ws, bs, loc_emb, scales, locs, out, npos);
}

// Round 7
// 12.612 us; speedup vs baseline: 1.0558x; 1.0558x over previous
//
#include <hip/hip_runtime.h>
#include <math.h>

// MultiBiasEncoder, fused single-kernel, s-parallel coefficient phase.
//   out[p,c] = sum_s A_s[p]*w[s,c] + sum_s B_s[p]*k[s,c] + sum_l lwn_l[p]*le[l,c] + cnst[p]
// Closed-form LN stats: mean = d*mw+mk ; var = d^2*vw + d*cwk2 + vk.
// Phase S: wave wid butterflies stats for s in {wid, wid+4, wid+8} -> LDS; ONE barrier.
// Phase A: 4 sub-lanes per position (all 64 lanes active). Sub-lane q owns
//          s in {q, q+4, q+8 (q==0 only)}; per-l shared values computed redundantly.
//          Only ssum (per l) and cnst need a 2-stage 4-lane shfl_xor combine.
//          A_s/B_s stay lane-local; scattered scalar LDS writes.
// Phase B: each wave applies its own 16 positions; 6 broadcast float4 reads + 25 FMA.
// scale-log factorization: log(|d|/s+eps) ~= max(log|d| - log s, log eps)  (verified R4-R6)

#define EPS_W 1e-6f
#define LN_EPS 1e-5f
#define LOG_EPS -13.815511f   // ln(1e-6)

constexpr int L = 5;
constexpr int S = 9;
constexpr int C = 64;
constexpr int PW = 16;    // positions per wave
constexpr int POS = 64;   // positions per block (4 waves)

__device__ __forceinline__ float fastrcp(float v) { return __builtin_amdgcn_rcpf(v); }

__global__ __launch_bounds__(256) void mbe6_kernel(
    const float* __restrict__ x,
    const float* __restrict__ ws,
    const float* __restrict__ bs,
    const float* __restrict__ loc_emb,
    const float* __restrict__ scales,
    const float* __restrict__ locs,
    float* __restrict__ out,
    int npos)
{
    const int tid = threadIdx.x;
    const int lane = tid & 63;
    const int wid = tid >> 6;

    __shared__ float4 statsLds[S][2];              // {mw,mk,vw,cwk2} {vk,log(scale),-,-}
    __shared__ alignas(16) float coefLds[POS][24]; // 24 coefs/position, row = 96 B

    const int gi = lane >> 2;   // position within wave (0..15)
    const int q = lane & 3;     // sub-lane: owns s = q, q+4, (q+8 if q==0)
    const int pbase = blockIdx.x * POS + wid * PW;
    const int p = pbase + gi;   // phase-A position for this lane's group

    // ---- early x broadcast load (4 lanes share one position) ----
    const int pc = p < npos ? p : (npos - 1);
    const float xv = x[pc];

    // ---- per-thread channel tables (lane == channel) ----
    float w[S], k[S], le[L];
#pragma unroll
    for (int s = 0; s < S; ++s) {
        w[s] = ws[s * C + lane];
        k[s] = bs[s * C + lane] * scales[s];
    }
#pragma unroll
    for (int l = 0; l < L; ++l) le[l] = loc_emb[l * C + lane];

    // ---- Phase S: distributed LN-stat butterflies (wave wid: s = wid, wid+4, wid+8) ----
    for (int s = wid; s < S; s += 4) {
        float a0 = w[s], a1 = k[s];
        float a2 = w[s] * w[s], a3 = w[s] * k[s], a4 = k[s] * k[s];
#pragma unroll
        for (int off = 32; off; off >>= 1) {
            a0 += __shfl_xor(a0, off);
            a1 += __shfl_xor(a1, off);
            a2 += __shfl_xor(a2, off);
            a3 += __shfl_xor(a3, off);
            a4 += __shfl_xor(a4, off);
        }
        if (lane == 0) {
            float mww = a0 * (1.0f / 64.0f);
            float mkk = a1 * (1.0f / 64.0f);
            statsLds[s][0] = make_float4(
                mww, mkk,
                fmaf(-mww, mww, a2 * (1.0f / 64.0f)),            // vw
                2.0f * fmaf(-mww, mkk, a3 * (1.0f / 64.0f)));    // cwk2
            statsLds[s][1] = make_float4(
                fmaf(-mkk, mkk, a4 * (1.0f / 64.0f)),            // vk
                __logf(scales[s]), 0.0f, 0.0f);
        }
    }
    __syncthreads();

    // ---- Phase A ----
    // per-lane (redundant across the 4 sub-lanes — same instruction slots):
    float d_[L], llog_[L], lwv_[L];
    float lwsum = 0.0f;
#pragma unroll
    for (int l = 0; l < L; ++l) {
        d_[l] = xv - locs[l];
        float ad = fabsf(d_[l]);
        lwv_[l] = fastrcp(__logf(ad + 1.0f) + EPS_W);
        lwsum += lwv_[l];
        llog_[l] = __logf(ad);   // -inf at ad=0 clamped by fmax below
    }
    const float rlw = fastrcp(lwsum);

    // own s-subset stats -> registers (j static, s = q + 4j runtime)
    float mwj[3], mkj[3], vwj[3], c2j[3], vkj[3], lgj[3];
#pragma unroll
    for (int j = 0; j < 3; ++j) {
        int s = q + 4 * j;
        if (s < S) {
            float4 a = statsLds[s][0];
            float4 b = statsLds[s][1];
            mwj[j] = a.x; mkj[j] = a.y; vwj[j] = a.z; c2j[j] = a.w;
            vkj[j] = b.x; lgj[j] = b.y;
        } else {
            mwj[j] = mkj[j] = vwj[j] = c2j[j] = lgj[j] = 0.0f;
            vkj[j] = 1.0f;
        }
    }

    // swv for own subset + partial scale-weight sums per l
    float swv[3][L];
    float pss[L];
#pragma unroll
    for (int l = 0; l < L; ++l) {
        float t = 0.0f;
#pragma unroll
        for (int j = 0; j < 3; ++j) {
            int s = q + 4 * j;
            float u = fmaxf(llog_[l] - lgj[j], LOG_EPS);   // ~ log(|d|/scale + eps)
            float v = fastrcp(fabsf(u) + EPS_W);
            v = (s < S) ? v : 0.0f;
            swv[j][l] = v;
            t += v;
        }
        pss[l] = t;
    }
    // complete ssum over all 9 s: 2-stage butterfly within the 4-lane group
#pragma unroll
    for (int l = 0; l < L; ++l) {
        pss[l] += __shfl_xor(pss[l], 1);
        pss[l] += __shfl_xor(pss[l], 2);
    }

    // accumulate A_s, B_s (lane-local) and cnst (combined at end)
    float Aj[3] = {0.0f, 0.0f, 0.0f};
    float Bj[3] = {0.0f, 0.0f, 0.0f};
    float cnst = 0.0f;
#pragma unroll
    for (int l = 0; l < L; ++l) {
        const float lwn = lwv_[l] * rlw;
        const float rss = fastrcp(pss[l]) * lwn;
        const float dd = d_[l];
        const float d2 = dd * dd;
#pragma unroll
        for (int j = 0; j < 3; ++j) {
            float mean = fmaf(dd, mwj[j], mkj[j]);
            float var = fmaf(d2, vwj[j], fmaf(dd, c2j[j], vkj[j]));
            float rstd = rsqrtf(var + LN_EPS);
            float alpha = swv[j][l] * rss * rstd;   // 0 for the s>=S slot
            Aj[j] = fmaf(alpha, dd, Aj[j]);
            Bj[j] += alpha;
            cnst = fmaf(-alpha, mean, cnst);
        }
    }
    cnst += __shfl_xor(cnst, 1);
    cnst += __shfl_xor(cnst, 2);

    // scattered scalar LDS writes (per-lane addressing)
    if (p < npos) {
        const int row = wid * PW + gi;
#pragma unroll
        for (int j = 0; j < 3; ++j) {
            int s = q + 4 * j;
            if (s < S) {
                coefLds[row][s] = Aj[j];
                coefLds[row][9 + s] = Bj[j];
            }
        }
        if (q == 0) {
#pragma unroll
            for (int l = 0; l < L; ++l) coefLds[row][18 + l] = lwv_[l] * rlw;
            coefLds[row][23] = cnst;
        }
    }
    // NO __syncthreads: each wave reads only rows it wrote itself (lgkmcnt-ordered).

    // ---- Phase B: each wave applies its own 16 positions ----
#pragma unroll
    for (int i = 0; i < PW; ++i) {
        const int pp = pbase + i;
        if (pp >= npos) break;
        const int row = wid * PW + i;
        const float4* cr = (const float4*)coefLds[row];
        float4 q0 = cr[0];
        float4 q1 = cr[1];
        float4 q2 = cr[2];
        float4 q3 = cr[3];
        float4 q4 = cr[4];
        float4 q5 = cr[5];
        // A[0..8]=q0.xyzw q1.xyzw q2.x ; B[0..8]=q2.yzw q3.xyzw q4.xy
        // lwn[0..4]=q4.zw q5.xyz ; cnst=q5.w
        float acc = q5.w;
        acc = fmaf(q0.x, w[0], acc); acc = fmaf(q0.y, w[1], acc);
        acc = fmaf(q0.z, w[2], acc); acc = fmaf(q0.w, w[3], acc);
        acc = fmaf(q1.x, w[4], acc); acc = fmaf(q1.y, w[5], acc);
        acc = fmaf(q1.z, w[6], acc); acc = fmaf(q1.w, w[7], acc);
        acc = fmaf(q2.x, w[8], acc);
        acc = fmaf(q2.y, k[0], acc); acc = fmaf(q2.z, k[1], acc);
        acc = fmaf(q2.w, k[2], acc); acc = fmaf(q3.x, k[3], acc);
        acc = fmaf(q3.y, k[4], acc); acc = fmaf(q3.z, k[5], acc);
        acc = fmaf(q3.w, k[6], acc); acc = fmaf(q4.x, k[7], acc);
        acc = fmaf(q4.y, k[8], acc);
        acc = fmaf(q4.z, le[0], acc); acc = fmaf(q4.w, le[1], acc);
        acc = fmaf(q5.x, le[2], acc); acc = fmaf(q5.y, le[3], acc);
        acc = fmaf(q5.z, le[4], acc);
        out[(size_t)pp * C + lane] = acc;
    }
}

extern "C" void kernel_launch(void* const* d_in, const int* in_sizes, int n_in,
                              void* d_out, int out_size, void* d_ws, size_t ws_size,
                              hipStream_t stream) {
    const float* x = (const float*)d_in[0];
    const float* ws = (const float*)d_in[1];
    const float* bs = (const float*)d_in[2];
    const float* loc_emb = (const float*)d_in[3];
    const float* scales = (const float*)d_in[4];
    const float* locs = (const float*)d_in[5];
    float* out = (float*)d_out;

    int npos = in_sizes[0];  // B*T = 16384
    int blocks = (npos + POS - 1) / POS;  // 256
    mbe6_kernel<<<blocks, 256, 0, stream>>>(x, ws, bs, loc_emb, scales, locs, out, npos);
}